// Round 1
// baseline (232.214 us; speedup 1.0000x reference)
//
#include <hip/hip_runtime.h>

// FacetCrossAttention: B=8, P=512, K=16, H=16, D=1024, DH=64
// Pipeline (all bf16 MFMA with f32 accum, memory-optimal factorization):
//   Wt[b,e,h] = sum_dh wk[e,h*64+dh] Q[b,h*64+dh];  c[b,h] = bk . Q_h
//   scores[h,k] = (G[k,:].Wt[:,h] + c)/8 + log(conf)   (per b,p; MFMA 16x16x32)
//   alpha = sparsemax_k (shuffle bitonic sort + scan + ballot)
//   Gbar[h,:] = sum_k alpha[h,k] G[k,:]                 (MFMA, alpha zero-padded k>=16)
//   AV[bp, h*64+c] = Gbar[bp,h,:] @ wv[:,h*64+c] + bv   (per-h GEMM)
//   y = AV @ wo + bo; LayerNorm in place.

typedef float f32x4 __attribute__((ext_vector_type(4)));
typedef short s16x4 __attribute__((ext_vector_type(4)));
typedef short s16x8 __attribute__((ext_vector_type(8)));

__device__ __forceinline__ unsigned short f2bf(float f) {
  unsigned u = __builtin_bit_cast(unsigned, f);
  u = (u + 0x7FFFu + ((u >> 16) & 1u)) >> 16;
  return (unsigned short)u;
}

__device__ __forceinline__ s16x8 pack8(s16x4 lo, s16x4 hi) {
  s16x8 r;
  r[0] = lo[0]; r[1] = lo[1]; r[2] = lo[2]; r[3] = lo[3];
  r[4] = hi[0]; r[5] = hi[1]; r[6] = hi[2]; r[7] = hi[3];
  return r;
}

// ---- K0: transpose wv and wo (f32 1024x1024) into bf16 [col][k] layouts ----
__global__ __launch_bounds__(256) void k_trans(
    const float* __restrict__ wv, const float* __restrict__ wo,
    unsigned short* __restrict__ wvt, unsigned short* __restrict__ wot) {
  __shared__ float ts[64][65];
  int bid = blockIdx.x;
  const float* src = (bid < 256) ? wv : wo;
  unsigned short* dst = (bid < 256) ? wvt : wot;
  int tile = bid & 255;
  int er = (tile >> 4) << 6;  // source row block (k dim)
  int cb = (tile & 15) << 6;  // source col block
  int t = threadIdx.x;
  int r = t >> 2, c0 = (t & 3) << 4;
#pragma unroll
  for (int j = 0; j < 16; j += 4) {
    f32x4 v = *(const f32x4*)&src[(long)(er + r) * 1024 + cb + c0 + j];
    ts[r][c0 + j + 0] = v[0];
    ts[r][c0 + j + 1] = v[1];
    ts[r][c0 + j + 2] = v[2];
    ts[r][c0 + j + 3] = v[3];
  }
  __syncthreads();
  s16x8 o0, o1;
#pragma unroll
  for (int j = 0; j < 8; ++j) o0[j] = (short)f2bf(ts[c0 + j][r]);
#pragma unroll
  for (int j = 0; j < 8; ++j) o1[j] = (short)f2bf(ts[c0 + 8 + j][r]);
  long ob = (long)(cb + r) * 1024 + er + c0;
  *(s16x8*)&dst[ob] = o0;
  *(s16x8*)&dst[ob + 8] = o1;
}

// ---- K1a: partial Q projection: qpart[b][eq][d] = sum_{e in eq} cq[b,e] wq[e,d] ----
__global__ __launch_bounds__(256) void k_qpart(
    const float* __restrict__ cq, const float* __restrict__ wq,
    float* __restrict__ qpart) {
  int eq = blockIdx.x, b = blockIdx.y, t = threadIdx.x;
  int d0 = t << 2;
  f32x4 acc = {0.f, 0.f, 0.f, 0.f};
#pragma unroll 4
  for (int i = 0; i < 64; ++i) {
    int e = (eq << 6) + i;
    float c = cq[(b << 10) + e];
    f32x4 w = *(const f32x4*)&wq[(long)e * 1024 + d0];
    acc += w * c;
  }
  *(f32x4*)&qpart[(long)((b << 4) + eq) * 1024 + d0] = acc;
}

// ---- K1b: Wt[b][h][e] (bf16) and c[b][h] ----
__global__ __launch_bounds__(256) void k_wtilde(
    const float* __restrict__ wk, const float* __restrict__ bk,
    const float* __restrict__ bq, const float* __restrict__ qpart,
    unsigned short* __restrict__ wt, float* __restrict__ cvec) {
  __shared__ float Qs[16][68];
  int et = blockIdx.x, b = blockIdx.y, t = threadIdx.x;
#pragma unroll
  for (int j = 0; j < 4; ++j) {
    int d = t + (j << 8);
    float s = bq[d];
    for (int q = 0; q < 16; ++q) s += qpart[(long)((b << 4) + q) * 1024 + d];
    Qs[d >> 6][d & 63] = s;
  }
  __syncthreads();
  int h = t & 15, el = t >> 4;
#pragma unroll
  for (int ii = 0; ii < 8; ++ii) {
    int e = (et << 7) + (ii << 4) + el;
    const float* wr = &wk[(long)e * 1024 + (h << 6)];
    float s = 0.f;
#pragma unroll
    for (int d = 0; d < 64; d += 4) {
      f32x4 w = *(const f32x4*)&wr[d];
      s += w[0] * Qs[h][d] + w[1] * Qs[h][d + 1] + w[2] * Qs[h][d + 2] + w[3] * Qs[h][d + 3];
    }
    wt[(long)((b << 4) + h) * 1024 + e] = f2bf(s);
  }
  if (et == 0 && t < 16) {
    float s = 0.f;
    for (int d = 0; d < 64; ++d) s += bk[(t << 6) + d] * Qs[t][d];
    cvec[(b << 4) + t] = s;
  }
}

// ---- K2: per (b,p): scores -> sparsemax -> Gbar ----
#define GSTR 1028
__global__ __launch_bounds__(256, 2) void k_scores(
    const float* __restrict__ G, const float* __restrict__ conf,
    const unsigned short* __restrict__ wt, const float* __restrict__ cvec,
    float* __restrict__ alpha_out, unsigned short* __restrict__ gbar, int b0) {
  // smem layout: Gs[16][1028] | Ws[16][1028] | As[16][32]  (contiguous shorts; stray
  // B-fragment reads with kf in [16,32) land inside Ws = finite bf16, times alpha=0)
  __shared__ short smem[33408];
  __shared__ float fsm[1040];
  short* Gs = smem;
  short* Ws = smem + 16 * GSTR;
  short* As = smem + 32 * GSTR;
  float* ps = fsm;        // [4][16][16] partial scores
  float* lc = fsm + 1024; // [16] log conf

  int t = threadIdx.x;
  int lane = t & 63, w = t >> 6;
  int bp = blockIdx.x;
  long gbp = (long)b0 * 512 + bp;
  int b = (int)(gbp >> 9);
  const float* Grow = G + gbp * 16384;
  const unsigned short* wtb = wt + (long)b * 16384;

  // load Wt -> Ws
#pragma unroll
  for (int it = 0; it < 8; ++it) {
    int flat = (it << 11) + (t << 3);
    s16x8 v = *(const s16x8*)&wtb[flat];
    short* dst = &Ws[(flat >> 10) * GSTR + (flat & 1023)];
    *(s16x4*)dst = (s16x4){v[0], v[1], v[2], v[3]};
    *(s16x4*)(dst + 4) = (s16x4){v[4], v[5], v[6], v[7]};
  }
  if (t < 32) {  // zero row pads (e in [1024,1028))
    short* base = (t < 16) ? Gs : Ws;
    *(s16x4*)&base[(t & 15) * GSTR + 1024] = (s16x4){0, 0, 0, 0};
  }
  if (t < 16) lc[t] = logf(fmaxf(conf[gbp * 16 + t], 1e-6f));

  // load G -> Gs (bf16)
#pragma unroll
  for (int k = 0; k < 16; ++k) {
    f32x4 g = *(const f32x4*)&Grow[(k << 10) + (t << 2)];
    s16x4 h4;
    h4[0] = (short)f2bf(g[0]); h4[1] = (short)f2bf(g[1]);
    h4[2] = (short)f2bf(g[2]); h4[3] = (short)f2bf(g[3]);
    *(s16x4*)&Gs[k * GSTR + (t << 2)] = h4;
  }
  __syncthreads();

  // phase 1: scores^T[h][kf] partial over this wave's e-quarter
  int l15 = lane & 15, g4 = lane >> 4;
  f32x4 sc = {0.f, 0.f, 0.f, 0.f};
#pragma unroll
  for (int i = 0; i < 8; ++i) {
    int eb = (w << 8) + (i << 5) + (g4 << 3);
    int off = l15 * GSTR + eb;
    s16x8 avf = pack8(*(const s16x4*)&Ws[off], *(const s16x4*)&Ws[off + 4]); // A row=h
    s16x8 bvf = pack8(*(const s16x4*)&Gs[off], *(const s16x4*)&Gs[off + 4]); // B col=kf
    sc = __builtin_amdgcn_mfma_f32_16x16x32_bf16(avf, bvf, sc, 0, 0, 0);
  }
#pragma unroll
  for (int r = 0; r < 4; ++r)
    ps[(w << 8) + ((g4 << 2) + r) * 16 + l15] = sc[r];
  __syncthreads();

  // sparsemax: thread (h = t>>4, k = t&15); 16-lane groups via shuffles
  int h = t >> 4, k = t & 15;
  float z = (ps[h * 16 + k] + ps[256 + h * 16 + k] + ps[512 + h * 16 + k] +
             ps[768 + h * 16 + k] + cvec[b * 16 + h]) * 0.125f + lc[k];
  float v = z;
#pragma unroll
  for (int kk = 2; kk <= 16; kk <<= 1) {
#pragma unroll
    for (int j = kk >> 1; j > 0; j >>= 1) {
      float o = __shfl_xor(v, j, 64);
      bool dirDesc = ((l15 & kk) == 0);
      bool takeMax = (((l15 & j) == 0) == dirDesc);
      v = takeMax ? fmaxf(v, o) : fminf(v, o);
    }
  }
  float cs = v;  // inclusive scan of descending-sorted values
#pragma unroll
  for (int d = 1; d < 16; d <<= 1) {
    float o = __shfl_up(cs, (unsigned)d, 16);
    if (l15 >= d) cs += o;
  }
  bool sup = (1.0f + (float)(l15 + 1) * v) > cs;
  unsigned long long m = __ballot(sup);
  int gb16 = lane & 48;
  int ksup = (int)__popcll((m >> gb16) & 0xFFFFull);
  float csk = __shfl(cs, ksup - 1, 16);
  float tau = (csk - 1.0f) / (float)ksup;
  float a = fmaxf(z - tau, 0.0f);
  alpha_out[((gbp << 4) + h) * 16 + k] = a;
  As[(h << 5) + k] = (short)f2bf(a);
  As[(h << 5) + 16 + k] = 0;
  __syncthreads();

  // phase 2: Gbar^T chunks: D[e_loc][h] = sum_kf Gt[e][kf] * alpha[h][kf]
  s16x8 ab = *(const s16x8*)&As[(l15 << 5) + (g4 << 3)];  // B: col=h, kf strided
  unsigned short* gbo = gbar + ((long)bp << 14);
#pragma unroll 4
  for (int i = 0; i < 16; ++i) {
    int ebase = ((w << 4) + i) << 4;
    int eA = ebase + l15;
    s16x8 aa;  // A: row=e (lane&15), kf = g4*8+j (strided u16 reads = G transpose)
#pragma unroll
    for (int j = 0; j < 8; ++j) aa[j] = Gs[((g4 << 3) + j) * GSTR + eA];
    f32x4 d2 = __builtin_amdgcn_mfma_f32_16x16x32_bf16(
        aa, ab, (f32x4){0.f, 0.f, 0.f, 0.f}, 0, 0, 0);
    s16x4 o4;
    o4[0] = (short)f2bf(d2[0]); o4[1] = (short)f2bf(d2[1]);
    o4[2] = (short)f2bf(d2[2]); o4[3] = (short)f2bf(d2[3]);
    // D: col=h=lane&15, rows = 4 consecutive e -> packed 8B store
    *(s16x4*)&gbo[(l15 << 10) + ebase + (g4 << 2)] = o4;
  }
}

// ---- K3: AV[bp, h*64+c] = Gbar[bp,h,:] @ wvt[h*64+c,:] + bv ----
__global__ __launch_bounds__(256) void k_av(
    const unsigned short* __restrict__ gbar, const unsigned short* __restrict__ wvt,
    const float* __restrict__ bv, unsigned short* __restrict__ av, int b0) {
  __shared__ short Asm[64 * 40];
  __shared__ short Bsm[64 * 40];
  int tile = blockIdx.x, h = blockIdx.y, t = threadIdx.x;
  int lane = t & 63, w = t >> 6;
  int wm = w >> 1, wn = w & 1;
  int l15 = lane & 15, g4 = lane >> 4;
  f32x4 acc[2][2] = {};
  int lr = t >> 2, ls = (t & 3) << 3;
  const unsigned short* Ar = gbar + ((long)(tile * 64 + lr)) * 16384 + h * 1024;
  const unsigned short* Br = wvt + ((long)((h << 6) + lr)) * 1024;
  s16x8 a8 = *(const s16x8*)&Ar[ls];
  s16x8 b8 = *(const s16x8*)&Br[ls];
  for (int kb = 0; kb < 32; ++kb) {
    __syncthreads();
    *(s16x8*)&Asm[lr * 40 + ls] = a8;
    *(s16x8*)&Bsm[lr * 40 + ls] = b8;
    if (kb + 1 < 32) {
      a8 = *(const s16x8*)&Ar[((kb + 1) << 5) + ls];
      b8 = *(const s16x8*)&Br[((kb + 1) << 5) + ls];
    }
    __syncthreads();
    s16x8 afr[2], bfr[2];
#pragma unroll
    for (int im = 0; im < 2; ++im)
      afr[im] = *(const s16x8*)&Asm[(wm * 32 + im * 16 + l15) * 40 + (g4 << 3)];
#pragma unroll
    for (int in = 0; in < 2; ++in)
      bfr[in] = *(const s16x8*)&Bsm[(wn * 32 + in * 16 + l15) * 40 + (g4 << 3)];
#pragma unroll
    for (int im = 0; im < 2; ++im)
#pragma unroll
      for (int in = 0; in < 2; ++in)
        acc[im][in] = __builtin_amdgcn_mfma_f32_16x16x32_bf16(afr[im], bfr[in], acc[im][in], 0, 0, 0);
  }
#pragma unroll
  for (int in = 0; in < 2; ++in) {
    int colg = (h << 6) + wn * 32 + in * 16 + l15;
    float bvv = bv[colg];
#pragma unroll
    for (int im = 0; im < 2; ++im) {
      long rowg = (long)b0 * 512 + tile * 64 + wm * 32 + im * 16 + (g4 << 2);
#pragma unroll
      for (int r = 0; r < 4; ++r)
        av[(rowg + r) * 1024 + colg] = f2bf(acc[im][in][r] + bvv);
    }
  }
}

// ---- K4: y = AV @ wo + bo  (128x128 tiles) ----
__global__ __launch_bounds__(256) void k_out(
    const unsigned short* __restrict__ av, const unsigned short* __restrict__ wot,
    const float* __restrict__ bo, float* __restrict__ y) {
  __shared__ short Asm[128 * 40];
  __shared__ short Bsm[128 * 40];
  int mt = blockIdx.x, nt = blockIdx.y, t = threadIdx.x;
  int lane = t & 63, w = t >> 6;
  int wm = w >> 1, wn = w & 1;
  int l15 = lane & 15, g4 = lane >> 4;
  f32x4 acc[4][4] = {};
  int lr = t >> 1, ls = (t & 1) << 4;
  const unsigned short* Ar = av + ((long)(mt * 128 + lr)) * 1024;
  const unsigned short* Br = wot + ((long)(nt * 128 + lr)) * 1024;
  s16x8 a0 = *(const s16x8*)&Ar[ls];
  s16x8 a1 = *(const s16x8*)&Ar[ls + 8];
  s16x8 b0 = *(const s16x8*)&Br[ls];
  s16x8 b1 = *(const s16x8*)&Br[ls + 8];
  for (int kb = 0; kb < 32; ++kb) {
    __syncthreads();
    short* pa = &Asm[lr * 40 + ls];
    *(s16x8*)pa = a0; *(s16x8*)(pa + 8) = a1;
    short* pb = &Bsm[lr * 40 + ls];
    *(s16x8*)pb = b0; *(s16x8*)(pb + 8) = b1;
    if (kb + 1 < 32) {
      a0 = *(const s16x8*)&Ar[((kb + 1) << 5) + ls];
      a1 = *(const s16x8*)&Ar[((kb + 1) << 5) + ls + 8];
      b0 = *(const s16x8*)&Br[((kb + 1) << 5) + ls];
      b1 = *(const s16x8*)&Br[((kb + 1) << 5) + ls + 8];
    }
    __syncthreads();
    s16x8 afr[4], bfr[4];
#pragma unroll
    for (int im = 0; im < 4; ++im)
      afr[im] = *(const s16x8*)&Asm[(wm * 64 + im * 16 + l15) * 40 + (g4 << 3)];
#pragma unroll
    for (int in = 0; in < 4; ++in)
      bfr[in] = *(const s16x8*)&Bsm[(wn * 64 + in * 16 + l15) * 40 + (g4 << 3)];
#pragma unroll
    for (int im = 0; im < 4; ++im)
#pragma unroll
      for (int in = 0; in < 4; ++in)
        acc[im][in] = __builtin_amdgcn_mfma_f32_16x16x32_bf16(afr[im], bfr[in], acc[im][in], 0, 0, 0);
  }
#pragma unroll
  for (int in = 0; in < 4; ++in) {
    int colg = nt * 128 + wn * 64 + in * 16 + l15;
    float bov = bo[colg];
#pragma unroll
    for (int im = 0; im < 4; ++im) {
      long rowg = mt * 128 + wm * 64 + im * 16 + (g4 << 2);
#pragma unroll
      for (int r = 0; r < 4; ++r)
        y[(rowg + r) * 1024 + colg] = acc[im][in][r] + bov;
    }
  }
}

// ---- K5: in-place LayerNorm over last dim ----
__global__ __launch_bounds__(256) void k_ln(
    float* __restrict__ y, const float* __restrict__ gamma,
    const float* __restrict__ beta) {
  int row = (blockIdx.x << 2) + (threadIdx.x >> 6);
  int lane = threadIdx.x & 63;
  float* yr = y + ((long)row << 10);
  f32x4 v[4];
  float s = 0.f, s2 = 0.f;
#pragma unroll
  for (int j = 0; j < 4; ++j) {
    v[j] = *(const f32x4*)&yr[(lane << 2) + (j << 8)];
#pragma unroll
    for (int q = 0; q < 4; ++q) { s += v[j][q]; s2 += v[j][q] * v[j][q]; }
  }
#pragma unroll
  for (int d = 1; d < 64; d <<= 1) {
    s += __shfl_xor(s, d, 64);
    s2 += __shfl_xor(s2, d, 64);
  }
  float mu = s * (1.0f / 1024.0f);
  float var = s2 * (1.0f / 1024.0f) - mu * mu;
  float rs = rsqrtf(var + 1e-5f);
#pragma unroll
  for (int j = 0; j < 4; ++j) {
    int f0 = (lane << 2) + (j << 8);
    f32x4 gm = *(const f32x4*)&gamma[f0];
    f32x4 bt = *(const f32x4*)&beta[f0];
    f32x4 o;
#pragma unroll
    for (int q = 0; q < 4; ++q) o[q] = (v[j][q] - mu) * rs * gm[q] + bt[q];
    *(f32x4*)&yr[f0] = o;
  }
}

extern "C" void kernel_launch(void* const* d_in, const int* in_sizes, int n_in,
                              void* d_out, int out_size, void* d_ws, size_t ws_size,
                              hipStream_t stream) {
  (void)in_sizes; (void)n_in; (void)out_size;
  const float* cq    = (const float*)d_in[0];
  const float* G     = (const float*)d_in[1];
  const float* conf  = (const float*)d_in[2];
  const float* wq    = (const float*)d_in[3];
  const float* bq    = (const float*)d_in[4];
  const float* wk    = (const float*)d_in[5];
  const float* bk    = (const float*)d_in[6];
  const float* wv    = (const float*)d_in[7];
  const float* bv    = (const float*)d_in[8];
  const float* wo    = (const float*)d_in[9];
  const float* bo    = (const float*)d_in[10];
  const float* gamma = (const float*)d_in[11];
  const float* beta  = (const float*)d_in[12];

  float* y = (float*)d_out;
  float* alpha = y + 4194304;  // out (8*512*1024) then alpha (8*512*16*16)

  char* p = (char*)d_ws;
  float* qpart = (float*)p;                 p += 8L * 16 * 1024 * 4;   // 512KB
  float* cvec  = (float*)p;                 p += 1024;                 // 512B used
  unsigned short* wt   = (unsigned short*)p; p += 8L * 16 * 1024 * 2;  // 256KB
  unsigned short* wvt  = (unsigned short*)p; p += 1024L * 1024 * 2;    // 2MB
  unsigned short* wot  = (unsigned short*)p; p += 1024L * 1024 * 2;    // 2MB
  unsigned short* av   = (unsigned short*)p; p += 4096L * 1024 * 2;    // 8MB
  unsigned short* gbar = (unsigned short*)p;
  size_t used = (size_t)(p - (char*)d_ws);
  size_t per_b = 512L * 16 * 1024 * 2;  // 16MB per batch of Gbar
  int nb = 1;
  if (ws_size >= used + 8 * per_b) nb = 8;
  else if (ws_size >= used + 4 * per_b) nb = 4;
  else if (ws_size >= used + 2 * per_b) nb = 2;

  hipLaunchKernelGGL(k_trans, dim3(512), dim3(256), 0, stream, wv, wo, wvt, wot);
  hipLaunchKernelGGL(k_qpart, dim3(16, 8), dim3(256), 0, stream, cq, wq, qpart);
  hipLaunchKernelGGL(k_wtilde, dim3(8, 8), dim3(256), 0, stream, wk, bk, bq, qpart, wt, cvec);
  for (int c = 0; c < 8; c += nb) {
    hipLaunchKernelGGL(k_scores, dim3(nb * 512), dim3(256), 0, stream,
                       G, conf, wt, cvec, alpha, gbar, c);
    hipLaunchKernelGGL(k_av, dim3(nb * 8, 16), dim3(256), 0, stream,
                       gbar, wvt, bv, av, c);
  }
  hipLaunchKernelGGL(k_out, dim3(32, 8), dim3(256), 0, stream, av, wot, bo, y);
  hipLaunchKernelGGL(k_ln, dim3(1024), dim3(256), 0, stream, y, gamma, beta);
}